// Round 2
// baseline (2334.096 us; speedup 1.0000x reference)
//
#include <hip/hip_runtime.h>
#include <hip/hip_bf16.h>

// Problem constants
#define NROWS 32768   // B*H*W = 32*32*32
#define CDIM  256
#define KCODES 8192
#define HWPB  1024    // H*W per batch
#define OUT_ELEMS 8388608   // 32*256*32*32
#define KSPLIT 4
// d_out layout: [0, 8388608) = out BCHW, [8388608] = loss, [8388609, +32768) = indices (as float)

// ---------------- inv-norm of codebook rows ----------------
__global__ __launch_bounds__(256) void vq_invnorm_kernel(
    const float* __restrict__ e, float* __restrict__ invn) {
  const int row  = blockIdx.x * 4 + (threadIdx.x >> 6);
  const int lane = threadIdx.x & 63;
  const float4 v = *reinterpret_cast<const float4*>(e + (size_t)row * CDIM + lane * 4);
  float s = v.x * v.x + v.y * v.y + v.z * v.z + v.w * v.w;
  #pragma unroll
  for (int o = 32; o > 0; o >>= 1) s += __shfl_down(s, o);
  if (lane == 0) invn[row] = 1.0f / fmaxf(sqrtf(s), 1e-12f);
}

// ---------------- fused fp32 GEMM + argmax ----------------
// Tile: BM=128 rows x BN=128 codes, 256 threads, 8x8 micro-tile, KC=16 c-chunk.
// Grid: (NROWS/128, KSPLIT) = 1024 blocks -> 4 blocks/CU.
#define BM 128
#define BN 128
#define KC 16

__global__ __launch_bounds__(256, 4) void vq_dist_argmax_kernel(
    const float* __restrict__ z, const float* __restrict__ e,
    const float* __restrict__ invn,
    float* __restrict__ bestval, int* __restrict__ bestidx) {
  __shared__ float as[KC][BM];
  __shared__ float bs[KC][BN + 4];

  const int t  = threadIdx.x;
  const int tx = t & 15;   // code group: codes tx*4..+3 and 64+tx*4..+3
  const int ty = t >> 4;   // row group: rows ty*8..+7
  const int n0 = blockIdx.x * BM;
  const int b   = n0 >> 10;      // batch (128 | 1024, never straddles)
  const int hw0 = n0 & 1023;
  const float* zbase = z + (size_t)b * (CDIM * HWPB) + hw0;
  const int kbeg = blockIdx.y * (KCODES / KSPLIT);

  float bv[8]; int bi[8];
  #pragma unroll
  for (int i = 0; i < 8; ++i) { bv[i] = -3.4e38f; bi[i] = 0; }

  // stage coords (float4 everywhere, <=2-way LDS banks)
  const int a_lm4 = (t & 31) * 4;   // m position (float4)
  const int a_cc  = t >> 5;         // 0..7, +8 on 2nd pass
  const int b_kk  = t >> 2;         // 0..63, +64 on 2nd pass
  const int b_q4  = (t & 3) * 4;    // c quad within chunk

  for (int kt = 0; kt < (KCODES / KSPLIT) / BN; ++kt) {
    const int k0 = kbeg + kt * BN;
    float acc[8][8];
    #pragma unroll
    for (int i = 0; i < 8; ++i)
      #pragma unroll
      for (int j = 0; j < 8; ++j) acc[i][j] = 0.f;

    for (int c0 = 0; c0 < CDIM; c0 += KC) {
      // stage A: 16x128 floats, one float4 per thread per pass
      #pragma unroll
      for (int p = 0; p < 2; ++p) {
        const int cc = a_cc + 8 * p;
        const float4 v = *reinterpret_cast<const float4*>(
            zbase + (size_t)(c0 + cc) * HWPB + a_lm4);
        *reinterpret_cast<float4*>(&as[cc][a_lm4]) = v;
      }
      // stage B (transposed): 16x128 floats, one float4 per thread per pass
      #pragma unroll
      for (int p = 0; p < 2; ++p) {
        const int kk = b_kk + 64 * p;
        const float4 v = *reinterpret_cast<const float4*>(
            e + (size_t)(k0 + kk) * CDIM + c0 + b_q4);
        bs[b_q4 + 0][kk] = v.x;
        bs[b_q4 + 1][kk] = v.y;
        bs[b_q4 + 2][kk] = v.z;
        bs[b_q4 + 3][kk] = v.w;
      }
      __syncthreads();
      #pragma unroll
      for (int cc = 0; cc < KC; ++cc) {
        const float4 a0 = *reinterpret_cast<const float4*>(&as[cc][ty * 8]);
        const float4 a1 = *reinterpret_cast<const float4*>(&as[cc][ty * 8 + 4]);
        const float4 b0 = *reinterpret_cast<const float4*>(&bs[cc][tx * 4]);
        const float4 b1 = *reinterpret_cast<const float4*>(&bs[cc][64 + tx * 4]);
        const float a[8]  = {a0.x, a0.y, a0.z, a0.w, a1.x, a1.y, a1.z, a1.w};
        const float bb[8] = {b0.x, b0.y, b0.z, b0.w, b1.x, b1.y, b1.z, b1.w};
        #pragma unroll
        for (int i = 0; i < 8; ++i)
          #pragma unroll
          for (int j = 0; j < 8; ++j)
            acc[i][j] = fmaf(a[i], bb[j], acc[i][j]);
      }
      __syncthreads();
    }

    // scale by codebook inv-norm, update running argmax (first-max kept;
    // within-thread candidate k is strictly ascending, so strict > keeps first)
    #pragma unroll
    for (int j = 0; j < 8; ++j) {
      const int k = k0 + ((j < 4) ? (tx * 4 + j) : (64 + tx * 4 + (j - 4)));
      const float inv = invn[k];
      #pragma unroll
      for (int i = 0; i < 8; ++i) {
        const float v = acc[i][j] * inv;
        if (v > bv[i]) { bv[i] = v; bi[i] = k; }
      }
    }
  }

  // butterfly reduce across the 16 lanes sharing each row (tx dimension)
  #pragma unroll
  for (int m = 1; m < 16; m <<= 1) {
    #pragma unroll
    for (int i = 0; i < 8; ++i) {
      const float vo = __shfl_xor(bv[i], m);
      const int   io = __shfl_xor(bi[i], m);
      if (vo > bv[i] || (vo == bv[i] && io < bi[i])) { bv[i] = vo; bi[i] = io; }
    }
  }
  if (tx == 0) {
    #pragma unroll
    for (int i = 0; i < 8; ++i) {
      bestval[blockIdx.y * NROWS + n0 + ty * 8 + i] = bv[i];
      bestidx[blockIdx.y * NROWS + n0 + ty * 8 + i] = bi[i];
    }
  }
}

// ---------------- gather + out write + loss partial ----------------
__global__ __launch_bounds__(256) void vq_gather_loss_kernel(
    const float* __restrict__ z, const float* __restrict__ e,
    const float* __restrict__ bestval, const int* __restrict__ bestidx,
    float* __restrict__ out, float* __restrict__ lossacc) {
  __shared__ int sidx[64];
  const int t  = threadIdx.x;
  const int n0 = blockIdx.x * 64;
  if (t < 64) {
    const int n = n0 + t;
    float best = bestval[n];
    int   bid  = bestidx[n];
    #pragma unroll
    for (int p = 1; p < KSPLIT; ++p) {
      const float v = bestval[p * NROWS + n];
      const int  id = bestidx[p * NROWS + n];
      if (v > best) { best = v; bid = id; }  // ties -> lower part (smaller k)
    }
    sidx[t] = bid;
    out[OUT_ELEMS + 1 + n] = (float)bid;
  }
  __syncthreads();
  const int b    = n0 >> 10;
  const int hw0  = n0 & 1023;
  const int nsub = t & 63;
  const int cg   = t >> 6;
  const float* erow = e + (size_t)sidx[nsub] * CDIM;
  float lsum = 0.f;
  for (int c = cg; c < CDIM; c += 4) {
    const float  v   = erow[c];
    const size_t off = (size_t)b * (CDIM * HWPB) + (size_t)c * HWPB + hw0 + nsub;
    const float  d   = v - z[off];
    lsum += d * d;
    out[off] = v;
  }
  #pragma unroll
  for (int o = 32; o > 0; o >>= 1) lsum += __shfl_down(lsum, o);
  __shared__ float wsum[4];
  if ((t & 63) == 0) wsum[t >> 6] = lsum;
  __syncthreads();
  if (t == 0) atomicAdd(lossacc, wsum[0] + wsum[1] + wsum[2] + wsum[3]);
}

__global__ void vq_finalize_kernel(const float* __restrict__ lossacc,
                                   float* __restrict__ out) {
  out[OUT_ELEMS] = 1.25f * lossacc[0] / (float)OUT_ELEMS;
}

extern "C" void kernel_launch(void* const* d_in, const int* in_sizes, int n_in,
                              void* d_out, int out_size, void* d_ws, size_t ws_size,
                              hipStream_t stream) {
  const float* z = (const float*)d_in[0];        // [32,256,32,32]
  const float* e = (const float*)d_in[1];        // [8192,256]
  float* out = (float*)d_out;

  // workspace (floats): invn[8192] | bestval[KSPLIT*32768] | bestidx[KSPLIT*32768] | lossacc[1]
  float* invn    = (float*)d_ws;
  float* bestval = invn + KCODES;
  int*   bestidx = (int*)(bestval + KSPLIT * NROWS);
  float* lossacc = (float*)(bestidx + KSPLIT * NROWS);

  hipMemsetAsync(lossacc, 0, sizeof(float), stream);

  vq_invnorm_kernel<<<KCODES / 4, 256, 0, stream>>>(e, invn);

  dim3 grid(NROWS / BM, KSPLIT);
  vq_dist_argmax_kernel<<<grid, 256, 0, stream>>>(z, e, invn, bestval, bestidx);

  vq_gather_loss_kernel<<<NROWS / 64, 256, 0, stream>>>(z, e, bestval, bestidx,
                                                        out, lossacc);
  vq_finalize_kernel<<<1, 1, 0, stream>>>(lossacc, out);
}

// Round 3
// 1680.590 us; speedup vs baseline: 1.3889x; 1.3889x over previous
//
#include <hip/hip_runtime.h>
#include <hip/hip_bf16.h>

// Problem constants
#define NROWS 32768   // B*H*W = 32*32*32
#define CDIM  256
#define KCODES 8192
#define HWPB  1024    // H*W per batch
#define OUT_ELEMS 8388608   // 32*256*32*32
#define KSPLIT 4
// d_out layout: [0, 8388608) = out BCHW, [8388608] = loss, [8388609, +32768) = indices (as float)

// ---------------- inv-norm of codebook rows ----------------
__global__ __launch_bounds__(256) void vq_invnorm_kernel(
    const float* __restrict__ e, float* __restrict__ invn) {
  const int row  = blockIdx.x * 4 + (threadIdx.x >> 6);
  const int lane = threadIdx.x & 63;
  const float4 v = *reinterpret_cast<const float4*>(e + (size_t)row * CDIM + lane * 4);
  float s = v.x * v.x + v.y * v.y + v.z * v.z + v.w * v.w;
  #pragma unroll
  for (int o = 32; o > 0; o >>= 1) s += __shfl_down(s, o);
  if (lane == 0) invn[row] = 1.0f / fmaxf(sqrtf(s), 1e-12f);
}

// ---------------- fused fp32 GEMM + argmax ----------------
// Tile: BM=128 rows x BN=128 codes, 256 threads, 8x8 micro-tile, KC=16 c-chunk.
// Grid: (NROWS/128, KSPLIT) = 1024 blocks -> 4 blocks/CU.
// NOTE: no min-waves in launch_bounds — (256,4) forced VGPR=64 and spilled
// (round 2: WRITE_SIZE 2.4 GB of scratch traffic). Unconstrained alloc is ~84
// VGPR -> 5-6 waves/SIMD allowed; grid (4 blocks/CU) is the occupancy limit.
#define BM 128
#define BN 128
#define KC 16

__global__ __launch_bounds__(256) void vq_dist_argmax_kernel(
    const float* __restrict__ z, const float* __restrict__ e,
    const float* __restrict__ invn,
    float* __restrict__ bestval, int* __restrict__ bestidx) {
  __shared__ float as[KC][BM];
  __shared__ float bs[KC][BN + 4];

  const int t  = threadIdx.x;
  const int tx = t & 15;   // code group: codes tx*4..+3 and 64+tx*4..+3
  const int ty = t >> 4;   // row group: rows ty*8..+7
  const int n0 = blockIdx.x * BM;
  const int b   = n0 >> 10;      // batch (128 | 1024, never straddles)
  const int hw0 = n0 & 1023;
  const float* zbase = z + (size_t)b * (CDIM * HWPB) + hw0;
  const int kbeg = blockIdx.y * (KCODES / KSPLIT);

  float bv[8]; int bi[8];
  #pragma unroll
  for (int i = 0; i < 8; ++i) { bv[i] = -3.4e38f; bi[i] = 0; }

  // stage coords (float4 everywhere, <=2-way LDS banks)
  const int a_lm4 = (t & 31) * 4;   // m position (float4)
  const int a_cc  = t >> 5;         // 0..7, +8 on 2nd pass
  const int b_kk  = t >> 2;         // 0..63, +64 on 2nd pass
  const int b_q4  = (t & 3) * 4;    // c quad within chunk

  for (int kt = 0; kt < (KCODES / KSPLIT) / BN; ++kt) {
    const int k0 = kbeg + kt * BN;
    float acc[8][8];
    #pragma unroll
    for (int i = 0; i < 8; ++i)
      #pragma unroll
      for (int j = 0; j < 8; ++j) acc[i][j] = 0.f;

    for (int c0 = 0; c0 < CDIM; c0 += KC) {
      // stage A: 16x128 floats, one float4 per thread per pass
      #pragma unroll
      for (int p = 0; p < 2; ++p) {
        const int cc = a_cc + 8 * p;
        const float4 v = *reinterpret_cast<const float4*>(
            zbase + (size_t)(c0 + cc) * HWPB + a_lm4);
        *reinterpret_cast<float4*>(&as[cc][a_lm4]) = v;
      }
      // stage B (transposed): 16x128 floats, one float4 per thread per pass
      #pragma unroll
      for (int p = 0; p < 2; ++p) {
        const int kk = b_kk + 64 * p;
        const float4 v = *reinterpret_cast<const float4*>(
            e + (size_t)(k0 + kk) * CDIM + c0 + b_q4);
        bs[b_q4 + 0][kk] = v.x;
        bs[b_q4 + 1][kk] = v.y;
        bs[b_q4 + 2][kk] = v.z;
        bs[b_q4 + 3][kk] = v.w;
      }
      __syncthreads();
      #pragma unroll
      for (int cc = 0; cc < KC; ++cc) {
        const float4 a0 = *reinterpret_cast<const float4*>(&as[cc][ty * 8]);
        const float4 a1 = *reinterpret_cast<const float4*>(&as[cc][ty * 8 + 4]);
        const float4 b0 = *reinterpret_cast<const float4*>(&bs[cc][tx * 4]);
        const float4 b1 = *reinterpret_cast<const float4*>(&bs[cc][64 + tx * 4]);
        const float a[8]  = {a0.x, a0.y, a0.z, a0.w, a1.x, a1.y, a1.z, a1.w};
        const float bb[8] = {b0.x, b0.y, b0.z, b0.w, b1.x, b1.y, b1.z, b1.w};
        #pragma unroll
        for (int i = 0; i < 8; ++i)
          #pragma unroll
          for (int j = 0; j < 8; ++j)
            acc[i][j] = fmaf(a[i], bb[j], acc[i][j]);
      }
      __syncthreads();
    }

    // scale by codebook inv-norm, update running argmax (first-max kept;
    // within-thread candidate k is strictly ascending, so strict > keeps first)
    #pragma unroll
    for (int j = 0; j < 8; ++j) {
      const int k = k0 + ((j < 4) ? (tx * 4 + j) : (64 + tx * 4 + (j - 4)));
      const float inv = invn[k];
      #pragma unroll
      for (int i = 0; i < 8; ++i) {
        const float v = acc[i][j] * inv;
        if (v > bv[i]) { bv[i] = v; bi[i] = k; }
      }
    }
  }

  // butterfly reduce across the 16 lanes sharing each row (tx dimension)
  #pragma unroll
  for (int m = 1; m < 16; m <<= 1) {
    #pragma unroll
    for (int i = 0; i < 8; ++i) {
      const float vo = __shfl_xor(bv[i], m);
      const int   io = __shfl_xor(bi[i], m);
      if (vo > bv[i] || (vo == bv[i] && io < bi[i])) { bv[i] = vo; bi[i] = io; }
    }
  }
  if (tx == 0) {
    #pragma unroll
    for (int i = 0; i < 8; ++i) {
      bestval[blockIdx.y * NROWS + n0 + ty * 8 + i] = bv[i];
      bestidx[blockIdx.y * NROWS + n0 + ty * 8 + i] = bi[i];
    }
  }
}

// ---------------- gather + out write + loss partial ----------------
__global__ __launch_bounds__(256) void vq_gather_loss_kernel(
    const float* __restrict__ z, const float* __restrict__ e,
    const float* __restrict__ bestval, const int* __restrict__ bestidx,
    float* __restrict__ out, float* __restrict__ lossacc) {
  __shared__ int sidx[64];
  const int t  = threadIdx.x;
  const int n0 = blockIdx.x * 64;
  if (t < 64) {
    const int n = n0 + t;
    float best = bestval[n];
    int   bid  = bestidx[n];
    #pragma unroll
    for (int p = 1; p < KSPLIT; ++p) {
      const float v = bestval[p * NROWS + n];
      const int  id = bestidx[p * NROWS + n];
      if (v > best) { best = v; bid = id; }  // ties -> lower part (smaller k)
    }
    sidx[t] = bid;
    out[OUT_ELEMS + 1 + n] = (float)bid;
  }
  __syncthreads();
  const int b    = n0 >> 10;
  const int hw0  = n0 & 1023;
  const int nsub = t & 63;
  const int cg   = t >> 6;
  const float* erow = e + (size_t)sidx[nsub] * CDIM;
  float lsum = 0.f;
  for (int c = cg; c < CDIM; c += 4) {
    const float  v   = erow[c];
    const size_t off = (size_t)b * (CDIM * HWPB) + (size_t)c * HWPB + hw0 + nsub;
    const float  d   = v - z[off];
    lsum += d * d;
    out[off] = v;
  }
  #pragma unroll
  for (int o = 32; o > 0; o >>= 1) lsum += __shfl_down(lsum, o);
  __shared__ float wsum[4];
  if ((t & 63) == 0) wsum[t >> 6] = lsum;
  __syncthreads();
  if (t == 0) atomicAdd(lossacc, wsum[0] + wsum[1] + wsum[2] + wsum[3]);
}

__global__ void vq_finalize_kernel(const float* __restrict__ lossacc,
                                   float* __restrict__ out) {
  out[OUT_ELEMS] = 1.25f * lossacc[0] / (float)OUT_ELEMS;
}

extern "C" void kernel_launch(void* const* d_in, const int* in_sizes, int n_in,
                              void* d_out, int out_size, void* d_ws, size_t ws_size,
                              hipStream_t stream) {
  const float* z = (const float*)d_in[0];        // [32,256,32,32]
  const float* e = (const float*)d_in[1];        // [8192,256]
  float* out = (float*)d_out;

  // workspace (floats): invn[8192] | bestval[KSPLIT*32768] | bestidx[KSPLIT*32768] | lossacc[1]
  float* invn    = (float*)d_ws;
  float* bestval = invn + KCODES;
  int*   bestidx = (int*)(bestval + KSPLIT * NROWS);
  float* lossacc = (float*)(bestidx + KSPLIT * NROWS);

  hipMemsetAsync(lossacc, 0, sizeof(float), stream);

  vq_invnorm_kernel<<<KCODES / 4, 256, 0, stream>>>(e, invn);

  dim3 grid(NROWS / BM, KSPLIT);
  vq_dist_argmax_kernel<<<grid, 256, 0, stream>>>(z, e, invn, bestval, bestidx);

  vq_gather_loss_kernel<<<NROWS / 64, 256, 0, stream>>>(z, e, bestval, bestidx,
                                                        out, lossacc);
  vq_finalize_kernel<<<1, 1, 0, stream>>>(lossacc, out);
}